// Round 2
// baseline (806.566 us; speedup 1.0000x reference)
//
#include <hip/hip_runtime.h>

#define D 32
#define SCAN_T 1024

// ---------------- counting ----------------
__global__ void count_kernel(const int* __restrict__ src, const int* __restrict__ dst,
                             int* __restrict__ degI, int* __restrict__ cntI, int E) {
    int j = blockIdx.x * blockDim.x + threadIdx.x;
    if (j < E) {
        atomicAdd(&degI[dst[j]], 1);
        atomicAdd(&cntI[src[j]], 1);
    }
}

// Exclusive scan of degI -> rowD/curD and cntI -> rowS/curS. Single block.
__global__ void scan2_kernel(const int* __restrict__ degI, const int* __restrict__ cntI,
                             int* __restrict__ rowD, int* __restrict__ curD,
                             int* __restrict__ rowS, int* __restrict__ curS, int N) {
    __shared__ int sums[SCAN_T];
    int t = threadIdx.x;
    int C = (N + SCAN_T - 1) / SCAN_T;
    for (int phase = 0; phase < 2; ++phase) {
        const int* in = phase ? cntI : degI;
        int* row = phase ? rowS : rowD;
        int* cur = phase ? curS : curD;
        int start = t * C;
        int local = 0;
        for (int k = 0; k < C; ++k) {
            int i = start + k;
            if (i < N) local += in[i];
        }
        sums[t] = local;
        __syncthreads();
        for (int off = 1; off < SCAN_T; off <<= 1) {
            int v = (t >= off) ? sums[t - off] : 0;
            __syncthreads();
            sums[t] += v;
            __syncthreads();
        }
        int run = (t == 0) ? 0 : sums[t - 1];
        for (int k = 0; k < C; ++k) {
            int i = start + k;
            if (i < N) {
                row[i] = run;
                cur[i] = run;
                run += in[i];
            }
        }
        if (t == SCAN_T - 1) row[N] = run;
        __syncthreads();
    }
}

// Counting-sort edges into two CSR adjacency arrays (order within bucket arbitrary).
__global__ void bucket_kernel(const int* __restrict__ src, const int* __restrict__ dst,
                              int* __restrict__ curD, int* __restrict__ curS,
                              int* __restrict__ srcByDst, int* __restrict__ dstBySrc, int E) {
    int j = blockIdx.x * blockDim.x + threadIdx.x;
    if (j < E) {
        int s = src[j], d = dst[j];
        int p1 = atomicAdd(&curD[d], 1);
        srcByDst[p1] = s;
        int p2 = atomicAdd(&curS[s], 1);
        dstBySrc[p2] = d;
    }
}

__global__ void dinv_kernel(const int* __restrict__ rowD, float* __restrict__ dinv, int N) {
    int i = blockIdx.x * blockDim.x + threadIdx.x;
    if (i < N) dinv[i] = rsqrtf((float)(rowD[i + 1] - rowD[i] + 1));  // +1 self-loop
}

// hs[i][d] = (X[i] @ W)[d] * dinv[i]; 8 rows per 256-thread block
__global__ void matmul_scale_kernel(const float* __restrict__ X, const float* __restrict__ W,
                                    const float* __restrict__ dinv, float* __restrict__ hs,
                                    int N) {
    __shared__ float Wl[D * D];
    __shared__ float Xl[8 * D];
    int tid = threadIdx.x;
    for (int k = tid; k < D * D; k += 256) Wl[k] = W[k];
    int row0 = blockIdx.x * 8;
    int g = row0 * D + tid;
    Xl[tid] = (g < N * D) ? X[g] : 0.f;
    __syncthreads();
    int r = tid >> 5;
    int d = tid & 31;
    int row = row0 + r;
    if (row < N) {
        float acc = 0.f;
        #pragma unroll
        for (int k = 0; k < D; ++k) acc += Xl[r * D + k] * Wl[k * D + d];
        hs[row * D + d] = acc * dinv[row];
    }
}

// Per-node gather: h2[i] = relu(dinv[i]*(sum_{in-edges} hs[src] + hs[i]) + b)
__global__ void conv_gather_kernel(const int* __restrict__ rowD, const int* __restrict__ srcByDst,
                                   const float* __restrict__ hs, const float* __restrict__ dinv,
                                   const float* __restrict__ b, float* __restrict__ h2, int N) {
    int node = blockIdx.x * 4 + (threadIdx.x >> 6);
    if (node >= N) return;
    int lane = threadIdx.x & 63;
    int half = lane >> 5, d = lane & 31;
    int s = rowD[node], e = rowD[node + 1];
    float acc = 0.f;
    for (int k = s + half; k < e; k += 2)
        acc += hs[srcByDst[k] * D + d];
    acc += __shfl_xor(acc, 32);
    if (half == 0) {
        float v = dinv[node] * (acc + hs[node * D + d]) + b[d];
        h2[node * D + d] = fmaxf(v, 0.f);
    }
}

// Per-node gather: out[i] = tanh( sum_{out-edges}(h2[i]-h2[dst])^2 / max(outdeg,1) )
__global__ void pow_gather_kernel(const int* __restrict__ rowS, const int* __restrict__ dstBySrc,
                                  const float* __restrict__ h2, float* __restrict__ out, int N) {
    int node = blockIdx.x * 4 + (threadIdx.x >> 6);
    if (node >= N) return;
    int lane = threadIdx.x & 63;
    int half = lane >> 5, d = lane & 31;
    int s = rowS[node], e = rowS[node + 1];
    float hval = h2[node * D + d];
    float acc = 0.f;
    for (int k = s + half; k < e; k += 2) {
        float v = hval - h2[dstBySrc[k] * D + d];
        acc += v * v;
    }
    acc += __shfl_xor(acc, 32);
    if (half == 0) {
        float c = fmaxf((float)(e - s), 1.f);
        out[node * D + d] = tanhf(acc / c);
    }
}

// ---------------- fallback (atomic path, round-1) ----------------
__global__ void fb_dinv_kernel(const int* __restrict__ degI, float* __restrict__ dinv, int N) {
    int i = blockIdx.x * blockDim.x + threadIdx.x;
    if (i < N) dinv[i] = rsqrtf((float)(degI[i] + 1));
}
__global__ void fb_scatter_conv(const int* __restrict__ src, const int* __restrict__ dst,
                                const float* __restrict__ hs, float* __restrict__ S, int ED) {
    int idx = blockIdx.x * blockDim.x + threadIdx.x;
    if (idx < ED) {
        int j = idx >> 5, d = idx & 31;
        atomicAdd(&S[dst[j] * D + d], hs[src[j] * D + d]);
    }
}
__global__ void fb_h2(float* __restrict__ S, const float* __restrict__ hs,
                      const float* __restrict__ dinv, const float* __restrict__ b, int ND) {
    int idx = blockIdx.x * blockDim.x + threadIdx.x;
    if (idx < ND) {
        int i = idx >> 5, d = idx & 31;
        float v = dinv[i] * (S[idx] + hs[idx]) + b[d];
        S[idx] = fmaxf(v, 0.f);
    }
}
__global__ void fb_edge_pow(const int* __restrict__ src, const int* __restrict__ dst,
                            const float* __restrict__ h2, float* __restrict__ out, int ED) {
    int idx = blockIdx.x * blockDim.x + threadIdx.x;
    if (idx < ED) {
        int j = idx >> 5, d = idx & 31;
        float v = h2[src[j] * D + d] - h2[dst[j] * D + d];
        atomicAdd(&out[src[j] * D + d], v * v);
    }
}
__global__ void fb_finalize(float* __restrict__ out, const int* __restrict__ cntI, int ND) {
    int idx = blockIdx.x * blockDim.x + threadIdx.x;
    if (idx < ND) {
        int i = idx >> 5;
        float c = fmaxf((float)cntI[i], 1.f);
        out[idx] = tanhf(out[idx] / c);
    }
}

extern "C" void kernel_launch(void* const* d_in, const int* in_sizes, int n_in,
                              void* d_out, int out_size, void* d_ws, size_t ws_size,
                              hipStream_t stream) {
    const float* X  = (const float*)d_in[0];
    const int*   ei = (const int*)d_in[1];
    const float* W  = (const float*)d_in[2];
    const float* b  = (const float*)d_in[3];
    int N = in_sizes[0] / D;
    int E = in_sizes[1] / 2;
    const int* src = ei;
    const int* dst = ei + E;
    float* out = (float*)d_out;

    size_t ND = (size_t)N * D;

    // CSR-path workspace layout
    float* hs   = (float*)d_ws;                 // ND
    float* h2   = hs + ND;                      // ND
    float* dinv = h2 + ND;                      // N
    int*   degI = (int*)(dinv + N);             // N
    int*   cntI = degI + N;                     // N
    int*   rowD = cntI + N;                     // N+1
    int*   rowS = rowD + N + 1;                 // N+1
    int*   curD = rowS + N + 1;                 // N
    int*   curS = curD + N;                     // N
    int*   srcByDst = curS + N;                 // E
    int*   dstBySrc = srcByDst + E;             // E
    size_t need = (2 * ND + 7 * (size_t)N + 2 + 2 * (size_t)E) * 4;

    if (ws_size >= need) {
        hipMemsetAsync(degI, 0, (size_t)2 * N * sizeof(int), stream);
        count_kernel<<<(E + 255) / 256, 256, 0, stream>>>(src, dst, degI, cntI, E);
        scan2_kernel<<<1, SCAN_T, 0, stream>>>(degI, cntI, rowD, curD, rowS, curS, N);
        bucket_kernel<<<(E + 255) / 256, 256, 0, stream>>>(src, dst, curD, curS,
                                                           srcByDst, dstBySrc, E);
        dinv_kernel<<<(N + 255) / 256, 256, 0, stream>>>(rowD, dinv, N);
        matmul_scale_kernel<<<(N + 7) / 8, 256, 0, stream>>>(X, W, dinv, hs, N);
        conv_gather_kernel<<<(N + 3) / 4, 256, 0, stream>>>(rowD, srcByDst, hs, dinv, b, h2, N);
        pow_gather_kernel<<<(N + 3) / 4, 256, 0, stream>>>(rowS, dstBySrc, h2, out, N);
    } else {
        // fallback: round-1 atomic path (13.4 MB workspace)
        float* S = h2;
        hipMemsetAsync(S, 0, ND * sizeof(float), stream);
        hipMemsetAsync(degI, 0, (size_t)2 * N * sizeof(int), stream);
        hipMemsetAsync(d_out, 0, ND * sizeof(float), stream);
        int EDi = E * D, NDi = (int)ND;
        count_kernel<<<(E + 255) / 256, 256, 0, stream>>>(src, dst, degI, cntI, E);
        fb_dinv_kernel<<<(N + 255) / 256, 256, 0, stream>>>(degI, dinv, N);
        matmul_scale_kernel<<<(N + 7) / 8, 256, 0, stream>>>(X, W, dinv, hs, N);
        fb_scatter_conv<<<(EDi + 255) / 256, 256, 0, stream>>>(src, dst, hs, S, EDi);
        fb_h2<<<(NDi + 255) / 256, 256, 0, stream>>>(S, hs, dinv, b, NDi);
        fb_edge_pow<<<(EDi + 255) / 256, 256, 0, stream>>>(src, dst, S, out, EDi);
        fb_finalize<<<(NDi + 255) / 256, 256, 0, stream>>>(out, cntI, NDi);
    }
}

// Round 3
// 385.414 us; speedup vs baseline: 2.0927x; 2.0927x over previous
//
#include <hip/hip_runtime.h>

#define D 32
#define CSH 9       // 512 nodes per coarse bucket
#define NBMAX 128

// ---------------- per-node counts ----------------
__global__ void count_kernel(const int* __restrict__ src, const int* __restrict__ dst,
                             int* __restrict__ degI, int* __restrict__ cntI, int E) {
    int j = blockIdx.x * blockDim.x + threadIdx.x;
    if (j < E) {
        atomicAdd(&degI[dst[j]], 1);
        atomicAdd(&cntI[src[j]], 1);
    }
}

__global__ void dinv_kernel(const int* __restrict__ degI, float* __restrict__ dinv, int N) {
    int i = blockIdx.x * blockDim.x + threadIdx.x;
    if (i < N) dinv[i] = rsqrtf((float)(degI[i] + 1));  // +1 self-loop
}

// ---------------- 3-phase exclusive scan (degI->rowD, cntI->rowS) ----------------
__global__ void scan_reduce(const int* __restrict__ degI, const int* __restrict__ cntI,
                            int* __restrict__ bsum, int N, int nblk) {
    __shared__ int sh[512];
    int which = blockIdx.x >= nblk;
    int blk = blockIdx.x - which * nblk;
    const int* in = which ? cntI : degI;
    int i = blk * 512 + threadIdx.x;
    sh[threadIdx.x] = (i < N) ? in[i] : 0;
    __syncthreads();
    for (int off = 256; off > 0; off >>= 1) {
        if (threadIdx.x < off) sh[threadIdx.x] += sh[threadIdx.x + off];
        __syncthreads();
    }
    if (threadIdx.x == 0) bsum[which * NBMAX + blk] = sh[0];
}

__global__ void scan_mid(const int* __restrict__ bsum, int* __restrict__ boff,
                         int* __restrict__ rowD, int* __restrict__ rowS, int nblk, int N) {
    __shared__ int sh[256];
    int t = threadIdx.x;          // 256 threads: two independent 128-wide scans
    int w = t >> 7, l = t & 127;
    sh[t] = (l < nblk) ? bsum[w * NBMAX + l] : 0;
    __syncthreads();
    for (int off = 1; off < 128; off <<= 1) {
        int x = (l >= off) ? sh[w * 128 + l - off] : 0;
        __syncthreads();
        sh[t] += x;
        __syncthreads();
    }
    if (l < nblk) boff[w * NBMAX + l] = (l == 0) ? 0 : sh[w * 128 + l - 1];
    if (l == nblk - 1) {
        if (w == 0) rowD[N] = sh[t]; else rowS[N] = sh[t];
    }
}

__global__ void scan_final(const int* __restrict__ degI, const int* __restrict__ cntI,
                           const int* __restrict__ boff,
                           int* __restrict__ rowD, int* __restrict__ rowS, int N, int nblk) {
    __shared__ int sh[512];
    int which = blockIdx.x >= nblk;
    int blk = blockIdx.x - which * nblk;
    const int* in = which ? cntI : degI;
    int* row = which ? rowS : rowD;
    int t = threadIdx.x;
    int i = blk * 512 + t;
    sh[t] = (i < N) ? in[i] : 0;
    __syncthreads();
    for (int off = 1; off < 512; off <<= 1) {
        int x = (t >= off) ? sh[t - off] : 0;
        __syncthreads();
        sh[t] += x;
        __syncthreads();
    }
    if (i < N) row[i] = boff[which * NBMAX + blk] + ((t == 0) ? 0 : sh[t - 1]);
}

__global__ void init_gcur(const int* __restrict__ rowD, const int* __restrict__ rowS,
                          int* __restrict__ gCurD, int* __restrict__ gCurS, int N, int nb) {
    int b = blockIdx.x * blockDim.x + threadIdx.x;
    if (b < nb) {
        int node = min(b << CSH, N);
        gCurD[b] = rowD[node];
        gCurS[b] = rowS[node];
    }
}

// ---------------- two-level counting sort ----------------
// coarse: group edges by key>>CSH; runs written contiguously (low write amplification)
__global__ void coarse_scatter(const int* __restrict__ key, const int* __restrict__ pay,
                               int* __restrict__ gCur, int2* __restrict__ coarse, int E) {
    __shared__ int h[NBMAX];
    __shared__ int base[NBMAX];
    int t = threadIdx.x;
    if (t < NBMAX) h[t] = 0;
    __syncthreads();
    int k[4], p[4], lp[4];
    int j0 = blockIdx.x * 4096;
    #pragma unroll
    for (int u = 0; u < 4; ++u) {
        int j = j0 + u * 1024 + t;
        if (j < E) {
            k[u] = key[j];
            p[u] = pay[j];
            lp[u] = atomicAdd(&h[k[u] >> CSH], 1);
        }
    }
    __syncthreads();
    if (t < NBMAX && h[t] > 0) base[t] = atomicAdd(&gCur[t], h[t]);
    __syncthreads();
    #pragma unroll
    for (int u = 0; u < 4; ++u) {
        int j = j0 + u * 1024 + t;
        if (j < E) coarse[base[k[u] >> CSH] + lp[u]] = make_int2(k[u], p[u]);
    }
}

// fine: per coarse bucket, LDS cur counters; scattered writes confined to L2-hot region
__global__ void fine_scatter(const int2* __restrict__ coarse, const int* __restrict__ row,
                             int* __restrict__ adj, int N) {
    __shared__ int cur[512];
    int b = blockIdx.x;
    int nodeLo = b << CSH;
    int nodeHi = min(nodeLo + 512, N);
    int t = threadIdx.x;  // 1024
    if (t < nodeHi - nodeLo) cur[t] = row[nodeLo + t];
    __syncthreads();
    int lo = row[nodeLo];
    int hi = row[nodeHi];
    for (int kk = lo + t; kk < hi; kk += 1024) {
        int2 e = coarse[kk];
        int pos = atomicAdd(&cur[e.x - nodeLo], 1);
        adj[pos] = e.y;
    }
}

// ---------------- dense part ----------------
__global__ void matmul_scale_kernel(const float* __restrict__ X, const float* __restrict__ W,
                                    const float* __restrict__ dinv, float* __restrict__ hs,
                                    int N) {
    __shared__ float Wl[D * D];
    __shared__ float Xl[8 * D];
    int tid = threadIdx.x;
    for (int k = tid; k < D * D; k += 256) Wl[k] = W[k];
    int row0 = blockIdx.x * 8;
    int g = row0 * D + tid;
    Xl[tid] = (g < N * D) ? X[g] : 0.f;
    __syncthreads();
    int r = tid >> 5;
    int d = tid & 31;
    int row = row0 + r;
    if (row < N) {
        float acc = 0.f;
        #pragma unroll
        for (int k = 0; k < D; ++k) acc += Xl[r * D + k] * Wl[k * D + d];
        hs[row * D + d] = acc * dinv[row];
    }
}

// ---------------- gather passes ----------------
__global__ void conv_gather_kernel(const int* __restrict__ rowD, const int* __restrict__ srcByDst,
                                   const float* __restrict__ hs, const float* __restrict__ dinv,
                                   const float* __restrict__ b, float* __restrict__ h2, int N) {
    int node = blockIdx.x * 4 + (threadIdx.x >> 6);
    if (node >= N) return;
    int lane = threadIdx.x & 63;
    int half = lane >> 5, d = lane & 31;
    int s = rowD[node], e = rowD[node + 1];
    float acc = 0.f;
    for (int k = s + half; k < e; k += 2)
        acc += hs[srcByDst[k] * D + d];
    acc += __shfl_xor(acc, 32);
    if (half == 0) {
        float v = dinv[node] * (acc + hs[node * D + d]) + b[d];
        h2[node * D + d] = fmaxf(v, 0.f);
    }
}

__global__ void pow_gather_kernel(const int* __restrict__ rowS, const int* __restrict__ dstBySrc,
                                  const float* __restrict__ h2, float* __restrict__ out, int N) {
    int node = blockIdx.x * 4 + (threadIdx.x >> 6);
    if (node >= N) return;
    int lane = threadIdx.x & 63;
    int half = lane >> 5, d = lane & 31;
    int s = rowS[node], e = rowS[node + 1];
    float hval = h2[node * D + d];
    float acc = 0.f;
    for (int k = s + half; k < e; k += 2) {
        float v = hval - h2[dstBySrc[k] * D + d];
        acc += v * v;
    }
    acc += __shfl_xor(acc, 32);
    if (half == 0) {
        float c = fmaxf((float)(e - s), 1.f);
        out[node * D + d] = tanhf(acc / c);
    }
}

// ---------------- fallback (atomic path, round-1) ----------------
__global__ void fb_scatter_conv(const int* __restrict__ src, const int* __restrict__ dst,
                                const float* __restrict__ hs, float* __restrict__ S, int ED) {
    int idx = blockIdx.x * blockDim.x + threadIdx.x;
    if (idx < ED) {
        int j = idx >> 5, d = idx & 31;
        atomicAdd(&S[dst[j] * D + d], hs[src[j] * D + d]);
    }
}
__global__ void fb_h2(float* __restrict__ S, const float* __restrict__ hs,
                      const float* __restrict__ dinv, const float* __restrict__ b, int ND) {
    int idx = blockIdx.x * blockDim.x + threadIdx.x;
    if (idx < ND) {
        int i = idx >> 5, d = idx & 31;
        float v = dinv[i] * (S[idx] + hs[idx]) + b[d];
        S[idx] = fmaxf(v, 0.f);
    }
}
__global__ void fb_edge_pow(const int* __restrict__ src, const int* __restrict__ dst,
                            const float* __restrict__ h2, float* __restrict__ out, int ED) {
    int idx = blockIdx.x * blockDim.x + threadIdx.x;
    if (idx < ED) {
        int j = idx >> 5, d = idx & 31;
        float v = h2[src[j] * D + d] - h2[dst[j] * D + d];
        atomicAdd(&out[src[j] * D + d], v * v);
    }
}
__global__ void fb_finalize(float* __restrict__ out, const int* __restrict__ cntI, int ND) {
    int idx = blockIdx.x * blockDim.x + threadIdx.x;
    if (idx < ND) {
        int i = idx >> 5;
        float c = fmaxf((float)cntI[i], 1.f);
        out[idx] = tanhf(out[idx] / c);
    }
}

extern "C" void kernel_launch(void* const* d_in, const int* in_sizes, int n_in,
                              void* d_out, int out_size, void* d_ws, size_t ws_size,
                              hipStream_t stream) {
    const float* X  = (const float*)d_in[0];
    const int*   ei = (const int*)d_in[1];
    const float* W  = (const float*)d_in[2];
    const float* b  = (const float*)d_in[3];
    int N = in_sizes[0] / D;
    int E = in_sizes[1] / 2;
    const int* src = ei;
    const int* dst = ei + E;
    float* out = (float*)d_out;

    size_t ND = (size_t)N * D;
    int nb = (N + 511) >> CSH;      // coarse buckets (= scan blocks per array)

    // layout (int2 coarse first for 8B alignment)
    int2*  coarse  = (int2*)d_ws;                 // E int2 = 2E ints
    float* hs      = (float*)(coarse + E);        // ND
    float* h2      = hs + ND;                     // ND
    float* dinv    = h2 + ND;                     // N
    int*   degI    = (int*)(dinv + N);            // N
    int*   cntI    = degI + N;                    // N
    int*   rowD    = cntI + N;                    // N+1
    int*   rowS    = rowD + N + 1;                // N+1
    int*   bsum    = rowS + N + 1;                // 2*NBMAX
    int*   boff    = bsum + 2 * NBMAX;            // 2*NBMAX
    int*   gCurD   = boff + 2 * NBMAX;            // NBMAX
    int*   gCurS   = gCurD + NBMAX;               // NBMAX
    int*   srcByDst = gCurS + NBMAX;              // E
    int*   dstBySrc = srcByDst + E;               // E
    size_t need = ((size_t)4 * E + 2 * ND + 5 * (size_t)N + 2 + 6 * NBMAX) * 4;

    if (ws_size >= need && nb <= NBMAX) {
        hipMemsetAsync(degI, 0, (size_t)2 * N * sizeof(int), stream);
        count_kernel<<<(E + 255) / 256, 256, 0, stream>>>(src, dst, degI, cntI, E);
        dinv_kernel<<<(N + 255) / 256, 256, 0, stream>>>(degI, dinv, N);
        matmul_scale_kernel<<<(N + 7) / 8, 256, 0, stream>>>(X, W, dinv, hs, N);

        scan_reduce<<<2 * nb, 512, 0, stream>>>(degI, cntI, bsum, N, nb);
        scan_mid<<<1, 256, 0, stream>>>(bsum, boff, rowD, rowS, nb, N);
        scan_final<<<2 * nb, 512, 0, stream>>>(degI, cntI, boff, rowD, rowS, N, nb);
        init_gcur<<<1, NBMAX, 0, stream>>>(rowD, rowS, gCurD, gCurS, N, nb);

        int cgrid = (E + 4095) / 4096;
        coarse_scatter<<<cgrid, 1024, 0, stream>>>(dst, src, gCurD, coarse, E);
        fine_scatter<<<nb, 1024, 0, stream>>>(coarse, rowD, srcByDst, N);
        coarse_scatter<<<cgrid, 1024, 0, stream>>>(src, dst, gCurS, coarse, E);
        fine_scatter<<<nb, 1024, 0, stream>>>(coarse, rowS, dstBySrc, N);

        conv_gather_kernel<<<(N + 3) / 4, 256, 0, stream>>>(rowD, srcByDst, hs, dinv, b, h2, N);
        pow_gather_kernel<<<(N + 3) / 4, 256, 0, stream>>>(rowS, dstBySrc, h2, out, N);
    } else {
        // fallback: round-1 atomic path (needs ~13.4 MB at offset past coarse reuse)
        float* fhs  = (float*)d_ws;
        float* S    = fhs + ND;
        float* fdv  = S + ND;
        int*   fdeg = (int*)(fdv + N);
        int*   fcnt = fdeg + N;
        hipMemsetAsync(S, 0, ND * sizeof(float), stream);
        hipMemsetAsync(fdeg, 0, (size_t)2 * N * sizeof(int), stream);
        hipMemsetAsync(d_out, 0, ND * sizeof(float), stream);
        int EDi = E * D, NDi = (int)ND;
        count_kernel<<<(E + 255) / 256, 256, 0, stream>>>(src, dst, fdeg, fcnt, E);
        dinv_kernel<<<(N + 255) / 256, 256, 0, stream>>>(fdeg, fdv, N);
        matmul_scale_kernel<<<(N + 7) / 8, 256, 0, stream>>>(X, W, fdv, fhs, N);
        fb_scatter_conv<<<(EDi + 255) / 256, 256, 0, stream>>>(src, dst, fhs, S, EDi);
        fb_h2<<<(NDi + 255) / 256, 256, 0, stream>>>(S, fhs, fdv, b, NDi);
        fb_edge_pow<<<(EDi + 255) / 256, 256, 0, stream>>>(src, dst, S, out, EDi);
        fb_finalize<<<(NDi + 255) / 256, 256, 0, stream>>>(out, fcnt, NDi);
    }
}

// Round 4
// 231.432 us; speedup vs baseline: 3.4851x; 1.6653x over previous
//
#include <hip/hip_runtime.h>

#define D 32
#define CSH 9                      // 512 nodes per coarse bucket
#define PSH 23                     // payload bits (node id) -> N must be <= 2^23
#define PMASK ((1u << PSH) - 1u)
#define NBMAX 128

// ---- coarse bucket counts for both directions (LDS histogram) ----
__global__ void ccount_kernel(const int* __restrict__ src, const int* __restrict__ dst,
                              int* __restrict__ bktTotD, int* __restrict__ bktTotS, int E) {
    __shared__ int hD[NBMAX], hS[NBMAX];
    int t = threadIdx.x;
    if (t < NBMAX) { hD[t] = 0; hS[t] = 0; }
    __syncthreads();
    int j0 = blockIdx.x * 4096;
    #pragma unroll
    for (int u = 0; u < 4; ++u) {
        int j = j0 + u * 1024 + t;
        if (j < E) {
            atomicAdd(&hD[dst[j] >> CSH], 1);
            atomicAdd(&hS[src[j] >> CSH], 1);
        }
    }
    __syncthreads();
    if (t < NBMAX) {
        if (hD[t]) atomicAdd(&bktTotD[t], hD[t]);
        if (hS[t]) atomicAdd(&bktTotS[t], hS[t]);
    }
}

// ---- single-block scan of bucket totals -> coarse offsets + cursors ----
__global__ void cscan_kernel(const int* __restrict__ bktTotD, const int* __restrict__ bktTotS,
                             int* __restrict__ coffD, int* __restrict__ coffS,
                             int* __restrict__ gCurD, int* __restrict__ gCurS,
                             int* __restrict__ rowD, int* __restrict__ rowS,
                             int nb, int N, int E) {
    __shared__ int sh[256];
    int t = threadIdx.x;              // 256: two 128-wide scans
    int w = t >> 7, l = t & 127;
    const int* in = w ? bktTotS : bktTotD;
    sh[t] = (l < nb) ? in[l] : 0;
    __syncthreads();
    for (int off = 1; off < 128; off <<= 1) {
        int x = (l >= off) ? sh[t - off] : 0;
        __syncthreads();
        sh[t] += x;
        __syncthreads();
    }
    int* coff = w ? coffS : coffD;
    int* gcur = w ? gCurS : gCurD;
    if (l < nb) {
        int excl = (l == 0) ? 0 : sh[t - 1];
        coff[l] = excl;
        gcur[l] = excl;
        if (l == nb - 1) coff[nb] = sh[t];
    }
    if (t == 0) { rowD[N] = E; rowS[N] = E; }
}

// ---- merged coarse scatter: one edge-list read, both directions ----
__global__ void coarse_scatter(const int* __restrict__ src, const int* __restrict__ dst,
                               int* __restrict__ gCurD, int* __restrict__ gCurS,
                               unsigned* __restrict__ coarseD, unsigned* __restrict__ coarseS,
                               int E) {
    __shared__ int hD[NBMAX], hS[NBMAX], baseD[NBMAX], baseS[NBMAX];
    int t = threadIdx.x;
    if (t < NBMAX) { hD[t] = 0; hS[t] = 0; }
    __syncthreads();
    int s[4], d[4], lpD[4], lpS[4];
    int j0 = blockIdx.x * 4096;
    #pragma unroll
    for (int u = 0; u < 4; ++u) {
        int j = j0 + u * 1024 + t;
        if (j < E) {
            s[u] = src[j]; d[u] = dst[j];
            lpD[u] = atomicAdd(&hD[d[u] >> CSH], 1);
            lpS[u] = atomicAdd(&hS[s[u] >> CSH], 1);
        }
    }
    __syncthreads();
    if (t < NBMAX) {
        if (hD[t]) baseD[t] = atomicAdd(&gCurD[t], hD[t]);
        if (hS[t]) baseS[t] = atomicAdd(&gCurS[t], hS[t]);
    }
    __syncthreads();
    #pragma unroll
    for (int u = 0; u < 4; ++u) {
        int j = j0 + u * 1024 + t;
        if (j < E) {
            coarseD[baseD[d[u] >> CSH] + lpD[u]] =
                ((unsigned)(d[u] & 511) << PSH) | (unsigned)s[u];
            coarseS[baseS[s[u] >> CSH] + lpS[u]] =
                ((unsigned)(s[u] & 511) << PSH) | (unsigned)d[u];
        }
    }
}

// ---- fine pass: per-node counts + row offsets + dinv + scatter, all in one ----
__global__ void fine_build(const unsigned* __restrict__ coarseD, const unsigned* __restrict__ coarseS,
                           const int* __restrict__ coffD, const int* __restrict__ coffS,
                           int* __restrict__ rowD, int* __restrict__ rowS,
                           int* __restrict__ srcByDst, int* __restrict__ dstBySrc,
                           float* __restrict__ dinv, int N, int nb) {
    __shared__ int cnt[512];
    __shared__ int pre[512];
    int which = blockIdx.x >= nb;
    int b = blockIdx.x - which * nb;
    const unsigned* coarse = which ? coarseS : coarseD;
    const int* coff = which ? coffS : coffD;
    int* row = which ? rowS : rowD;
    int* adj = which ? dstBySrc : srcByDst;
    int t = threadIdx.x;   // 1024
    int nodeLo = b << CSH;
    int nNodes = min(512, N - nodeLo);
    if (t < 512) cnt[t] = 0;
    __syncthreads();
    int lo = coff[b], hi = coff[b + 1];
    for (int kk = lo + t; kk < hi; kk += 1024)
        atomicAdd(&cnt[coarse[kk] >> PSH], 1);
    __syncthreads();
    if (t < 512) pre[t] = cnt[t];
    __syncthreads();
    for (int off = 1; off < 512; off <<= 1) {
        int x = 0;
        if (t < 512 && t >= off) x = pre[t - off];
        __syncthreads();
        if (t < 512) pre[t] += x;
        __syncthreads();
    }
    int myexcl = 0, mydeg = 0;
    if (t < 512) { mydeg = cnt[t]; myexcl = pre[t] - mydeg; }
    if (t < nNodes) {
        row[nodeLo + t] = lo + myexcl;
        if (!which) dinv[nodeLo + t] = rsqrtf((float)(mydeg + 1));   // +1 self-loop
    }
    __syncthreads();
    if (t < 512) cnt[t] = lo + myexcl;   // cursors
    __syncthreads();
    for (int kk = lo + t; kk < hi; kk += 1024) {
        unsigned e = coarse[kk];
        int pos = atomicAdd(&cnt[e >> PSH], 1);
        adj[pos] = (int)(e & PMASK);
    }
}

// ---- dense part: hs[i] = (X[i] @ W) * dinv[i] ----
__global__ void matmul_scale_kernel(const float* __restrict__ X, const float* __restrict__ W,
                                    const float* __restrict__ dinv, float* __restrict__ hs,
                                    int N) {
    __shared__ float Wl[D * D];
    __shared__ float Xl[8 * D];
    int tid = threadIdx.x;
    for (int k = tid; k < D * D; k += 256) Wl[k] = W[k];
    int row0 = blockIdx.x * 8;
    int g = row0 * D + tid;
    Xl[tid] = (g < N * D) ? X[g] : 0.f;
    __syncthreads();
    int r = tid >> 5;
    int d = tid & 31;
    int row = row0 + r;
    if (row < N) {
        float acc = 0.f;
        #pragma unroll
        for (int k = 0; k < D; ++k) acc += Xl[r * D + k] * Wl[k * D + d];
        hs[row * D + d] = acc * dinv[row];
    }
}

// ---- gather passes ----
__global__ void conv_gather_kernel(const int* __restrict__ rowD, const int* __restrict__ srcByDst,
                                   const float* __restrict__ hs, const float* __restrict__ dinv,
                                   const float* __restrict__ b, float* __restrict__ h2, int N) {
    int node = blockIdx.x * 4 + (threadIdx.x >> 6);
    if (node >= N) return;
    int lane = threadIdx.x & 63;
    int half = lane >> 5, d = lane & 31;
    int s = rowD[node], e = rowD[node + 1];
    float acc = 0.f;
    for (int k = s + half; k < e; k += 2)
        acc += hs[srcByDst[k] * D + d];
    acc += __shfl_xor(acc, 32);
    if (half == 0) {
        float v = dinv[node] * (acc + hs[node * D + d]) + b[d];
        h2[node * D + d] = fmaxf(v, 0.f);
    }
}

__global__ void pow_gather_kernel(const int* __restrict__ rowS, const int* __restrict__ dstBySrc,
                                  const float* __restrict__ h2, float* __restrict__ out, int N) {
    int node = blockIdx.x * 4 + (threadIdx.x >> 6);
    if (node >= N) return;
    int lane = threadIdx.x & 63;
    int half = lane >> 5, d = lane & 31;
    int s = rowS[node], e = rowS[node + 1];
    float hval = h2[node * D + d];
    float acc = 0.f;
    for (int k = s + half; k < e; k += 2) {
        float v = hval - h2[dstBySrc[k] * D + d];
        acc += v * v;
    }
    acc += __shfl_xor(acc, 32);
    if (half == 0) {
        float c = fmaxf((float)(e - s), 1.f);
        out[node * D + d] = tanhf(acc / c);
    }
}

// ---------------- fallback (atomic path, round-1) ----------------
__global__ void fb_count(const int* __restrict__ src, const int* __restrict__ dst,
                         int* __restrict__ degI, int* __restrict__ cntI, int E) {
    int j = blockIdx.x * blockDim.x + threadIdx.x;
    if (j < E) {
        atomicAdd(&degI[dst[j]], 1);
        atomicAdd(&cntI[src[j]], 1);
    }
}
__global__ void fb_dinv(const int* __restrict__ degI, float* __restrict__ dinv, int N) {
    int i = blockIdx.x * blockDim.x + threadIdx.x;
    if (i < N) dinv[i] = rsqrtf((float)(degI[i] + 1));
}
__global__ void fb_scatter_conv(const int* __restrict__ src, const int* __restrict__ dst,
                                const float* __restrict__ hs, float* __restrict__ S, int ED) {
    int idx = blockIdx.x * blockDim.x + threadIdx.x;
    if (idx < ED) {
        int j = idx >> 5, d = idx & 31;
        atomicAdd(&S[dst[j] * D + d], hs[src[j] * D + d]);
    }
}
__global__ void fb_h2(float* __restrict__ S, const float* __restrict__ hs,
                      const float* __restrict__ dinv, const float* __restrict__ b, int ND) {
    int idx = blockIdx.x * blockDim.x + threadIdx.x;
    if (idx < ND) {
        int i = idx >> 5, d = idx & 31;
        float v = dinv[i] * (S[idx] + hs[idx]) + b[d];
        S[idx] = fmaxf(v, 0.f);
    }
}
__global__ void fb_edge_pow(const int* __restrict__ src, const int* __restrict__ dst,
                            const float* __restrict__ h2, float* __restrict__ out, int ED) {
    int idx = blockIdx.x * blockDim.x + threadIdx.x;
    if (idx < ED) {
        int j = idx >> 5, d = idx & 31;
        float v = h2[src[j] * D + d] - h2[dst[j] * D + d];
        atomicAdd(&out[src[j] * D + d], v * v);
    }
}
__global__ void fb_finalize(float* __restrict__ out, const int* __restrict__ cntI, int ND) {
    int idx = blockIdx.x * blockDim.x + threadIdx.x;
    if (idx < ND) {
        int i = idx >> 5;
        float c = fmaxf((float)cntI[i], 1.f);
        out[idx] = tanhf(out[idx] / c);
    }
}

extern "C" void kernel_launch(void* const* d_in, const int* in_sizes, int n_in,
                              void* d_out, int out_size, void* d_ws, size_t ws_size,
                              hipStream_t stream) {
    const float* X  = (const float*)d_in[0];
    const int*   ei = (const int*)d_in[1];
    const float* W  = (const float*)d_in[2];
    const float* b  = (const float*)d_in[3];
    int N = in_sizes[0] / D;
    int E = in_sizes[1] / 2;
    const int* src = ei;
    const int* dst = ei + E;
    float* out = (float*)d_out;

    size_t ND = (size_t)N * D;
    int nb = (N + 511) >> CSH;

    unsigned* coarseD = (unsigned*)d_ws;          // E
    unsigned* coarseS = coarseD + E;              // E
    int* srcByDst = (int*)(coarseS + E);          // E
    int* dstBySrc = srcByDst + E;                 // E
    float* hs   = (float*)(dstBySrc + E);         // ND
    float* h2   = hs + ND;                        // ND
    float* dinv = h2 + ND;                        // N
    int* rowD   = (int*)(dinv + N);               // N+1
    int* rowS   = rowD + N + 1;                   // N+1
    int* coffD  = rowS + N + 1;                   // NBMAX+1
    int* coffS  = coffD + NBMAX + 1;              // NBMAX+1
    int* gCurD  = coffS + NBMAX + 1;              // NBMAX
    int* gCurS  = gCurD + NBMAX;                  // NBMAX
    int* bktTotD = gCurS + NBMAX;                 // NBMAX
    int* bktTotS = bktTotD + NBMAX;               // NBMAX
    size_t need = ((size_t)4 * E + 2 * ND + 3 * (size_t)N + 2 + 6 * NBMAX + 2) * 4;

    if (ws_size >= need && nb <= NBMAX && N <= (1 << PSH)) {
        hipMemsetAsync(bktTotD, 0, (size_t)2 * NBMAX * sizeof(int), stream);
        int cgrid = (E + 4095) / 4096;
        ccount_kernel<<<cgrid, 1024, 0, stream>>>(src, dst, bktTotD, bktTotS, E);
        cscan_kernel<<<1, 256, 0, stream>>>(bktTotD, bktTotS, coffD, coffS,
                                            gCurD, gCurS, rowD, rowS, nb, N, E);
        coarse_scatter<<<cgrid, 1024, 0, stream>>>(src, dst, gCurD, gCurS,
                                                   coarseD, coarseS, E);
        fine_build<<<2 * nb, 1024, 0, stream>>>(coarseD, coarseS, coffD, coffS,
                                                rowD, rowS, srcByDst, dstBySrc, dinv, N, nb);
        matmul_scale_kernel<<<(N + 7) / 8, 256, 0, stream>>>(X, W, dinv, hs, N);
        conv_gather_kernel<<<(N + 3) / 4, 256, 0, stream>>>(rowD, srcByDst, hs, dinv, b, h2, N);
        pow_gather_kernel<<<(N + 3) / 4, 256, 0, stream>>>(rowS, dstBySrc, h2, out, N);
    } else {
        float* fhs  = (float*)d_ws;
        float* S    = fhs + ND;
        float* fdv  = S + ND;
        int*   fdeg = (int*)(fdv + N);
        int*   fcnt = fdeg + N;
        hipMemsetAsync(S, 0, ND * sizeof(float), stream);
        hipMemsetAsync(fdeg, 0, (size_t)2 * N * sizeof(int), stream);
        hipMemsetAsync(d_out, 0, ND * sizeof(float), stream);
        int EDi = E * D, NDi = (int)ND;
        fb_count<<<(E + 255) / 256, 256, 0, stream>>>(src, dst, fdeg, fcnt, E);
        fb_dinv<<<(N + 255) / 256, 256, 0, stream>>>(fdeg, fdv, N);
        matmul_scale_kernel<<<(N + 7) / 8, 256, 0, stream>>>(X, W, fdv, fhs, N);
        fb_scatter_conv<<<(EDi + 255) / 256, 256, 0, stream>>>(src, dst, fhs, S, EDi);
        fb_h2<<<(NDi + 255) / 256, 256, 0, stream>>>(S, fhs, fdv, b, NDi);
        fb_edge_pow<<<(EDi + 255) / 256, 256, 0, stream>>>(src, dst, S, out, EDi);
        fb_finalize<<<(NDi + 255) / 256, 256, 0, stream>>>(out, fcnt, NDi);
    }
}

// Round 5
// 156.931 us; speedup vs baseline: 5.1396x; 1.4747x over previous
//
#include <hip/hip_runtime.h>

#define D 32
#define CSH 9                      // 512 nodes per coarse bucket
#define PSH 23                     // payload bits (node id) -> N must be <= 2^23
#define PMASK ((1u << PSH) - 1u)
#define NBMAX 128

// ---- coarse bucket counts for both directions (LDS histogram) ----
__global__ void ccount_kernel(const int* __restrict__ src, const int* __restrict__ dst,
                              int* __restrict__ bktTotD, int* __restrict__ bktTotS, int E) {
    __shared__ int hD[NBMAX], hS[NBMAX];
    int t = threadIdx.x;
    if (t < NBMAX) { hD[t] = 0; hS[t] = 0; }
    __syncthreads();
    int j0 = blockIdx.x * 4096;
    #pragma unroll
    for (int u = 0; u < 4; ++u) {
        int j = j0 + u * 1024 + t;
        if (j < E) {
            atomicAdd(&hD[dst[j] >> CSH], 1);
            atomicAdd(&hS[src[j] >> CSH], 1);
        }
    }
    __syncthreads();
    if (t < NBMAX) {
        if (hD[t]) atomicAdd(&bktTotD[t], hD[t]);
        if (hS[t]) atomicAdd(&bktTotS[t], hS[t]);
    }
}

// ---- single-block scan of bucket totals -> coarse offsets + cursors ----
__global__ void cscan_kernel(const int* __restrict__ bktTotD, const int* __restrict__ bktTotS,
                             int* __restrict__ coffD, int* __restrict__ coffS,
                             int* __restrict__ gCurD, int* __restrict__ gCurS,
                             int* __restrict__ rowD, int* __restrict__ rowS,
                             int nb, int N, int E) {
    __shared__ int sh[256];
    int t = threadIdx.x;              // 256: two 128-wide scans
    int w = t >> 7, l = t & 127;
    const int* in = w ? bktTotS : bktTotD;
    sh[t] = (l < nb) ? in[l] : 0;
    __syncthreads();
    for (int off = 1; off < 128; off <<= 1) {
        int x = (l >= off) ? sh[t - off] : 0;
        __syncthreads();
        sh[t] += x;
        __syncthreads();
    }
    int* coff = w ? coffS : coffD;
    int* gcur = w ? gCurS : gCurD;
    if (l < nb) {
        int excl = (l == 0) ? 0 : sh[t - 1];
        coff[l] = excl;
        gcur[l] = excl;
        if (l == nb - 1) coff[nb] = sh[t];
    }
    if (t == 0) { rowD[N] = E; rowS[N] = E; }
}

// ---- merged coarse scatter: one edge-list read, both directions ----
__global__ void coarse_scatter(const int* __restrict__ src, const int* __restrict__ dst,
                               int* __restrict__ gCurD, int* __restrict__ gCurS,
                               unsigned* __restrict__ coarseD, unsigned* __restrict__ coarseS,
                               int E) {
    __shared__ int hD[NBMAX], hS[NBMAX], baseD[NBMAX], baseS[NBMAX];
    int t = threadIdx.x;
    if (t < NBMAX) { hD[t] = 0; hS[t] = 0; }
    __syncthreads();
    int s[4], d[4], lpD[4], lpS[4];
    int j0 = blockIdx.x * 4096;
    #pragma unroll
    for (int u = 0; u < 4; ++u) {
        int j = j0 + u * 1024 + t;
        if (j < E) {
            s[u] = src[j]; d[u] = dst[j];
            lpD[u] = atomicAdd(&hD[d[u] >> CSH], 1);
            lpS[u] = atomicAdd(&hS[s[u] >> CSH], 1);
        }
    }
    __syncthreads();
    if (t < NBMAX) {
        if (hD[t]) baseD[t] = atomicAdd(&gCurD[t], hD[t]);
        if (hS[t]) baseS[t] = atomicAdd(&gCurS[t], hS[t]);
    }
    __syncthreads();
    #pragma unroll
    for (int u = 0; u < 4; ++u) {
        int j = j0 + u * 1024 + t;
        if (j < E) {
            coarseD[baseD[d[u] >> CSH] + lpD[u]] =
                ((unsigned)(d[u] & 511) << PSH) | (unsigned)s[u];
            coarseS[baseS[s[u] >> CSH] + lpS[u]] =
                ((unsigned)(s[u] & 511) << PSH) | (unsigned)d[u];
        }
    }
}

// ---- fine pass: per-node counts + row offsets + dinv + scatter, all in one ----
__global__ void fine_build(const unsigned* __restrict__ coarseD, const unsigned* __restrict__ coarseS,
                           const int* __restrict__ coffD, const int* __restrict__ coffS,
                           int* __restrict__ rowD, int* __restrict__ rowS,
                           int* __restrict__ srcByDst, int* __restrict__ dstBySrc,
                           float* __restrict__ dinv, int N, int nb) {
    __shared__ int cnt[512];
    __shared__ int pre[512];
    int which = blockIdx.x >= nb;
    int b = blockIdx.x - which * nb;
    const unsigned* coarse = which ? coarseS : coarseD;
    const int* coff = which ? coffS : coffD;
    int* row = which ? rowS : rowD;
    int* adj = which ? dstBySrc : srcByDst;
    int t = threadIdx.x;   // 1024
    int nodeLo = b << CSH;
    int nNodes = min(512, N - nodeLo);
    if (t < 512) cnt[t] = 0;
    __syncthreads();
    int lo = coff[b], hi = coff[b + 1];
    for (int kk = lo + t; kk < hi; kk += 1024)
        atomicAdd(&cnt[coarse[kk] >> PSH], 1);
    __syncthreads();
    if (t < 512) pre[t] = cnt[t];
    __syncthreads();
    for (int off = 1; off < 512; off <<= 1) {
        int x = 0;
        if (t < 512 && t >= off) x = pre[t - off];
        __syncthreads();
        if (t < 512) pre[t] += x;
        __syncthreads();
    }
    int myexcl = 0, mydeg = 0;
    if (t < 512) { mydeg = cnt[t]; myexcl = pre[t] - mydeg; }
    if (t < nNodes) {
        row[nodeLo + t] = lo + myexcl;
        if (!which) dinv[nodeLo + t] = rsqrtf((float)(mydeg + 1));   // +1 self-loop
    }
    __syncthreads();
    if (t < 512) cnt[t] = lo + myexcl;   // cursors
    __syncthreads();
    for (int kk = lo + t; kk < hi; kk += 1024) {
        unsigned e = coarse[kk];
        int pos = atomicAdd(&cnt[e >> PSH], 1);
        adj[pos] = (int)(e & PMASK);
    }
}

// ---- dense part: hs[i] = (X[i] @ W) * dinv[i] ----
__global__ void matmul_scale_kernel(const float* __restrict__ X, const float* __restrict__ W,
                                    const float* __restrict__ dinv, float* __restrict__ hs,
                                    int N) {
    __shared__ float Wl[D * D];
    __shared__ float Xl[8 * D];
    int tid = threadIdx.x;
    for (int k = tid; k < D * D; k += 256) Wl[k] = W[k];
    int row0 = blockIdx.x * 8;
    int g = row0 * D + tid;
    Xl[tid] = (g < N * D) ? X[g] : 0.f;
    __syncthreads();
    int r = tid >> 5;
    int d = tid & 31;
    int row = row0 + r;
    if (row < N) {
        float acc = 0.f;
        #pragma unroll
        for (int k = 0; k < D; ++k) acc += Xl[r * D + k] * Wl[k * D + d];
        hs[row * D + d] = acc * dinv[row];
    }
}

// ---- gather passes (4x unrolled: 4 outstanding gathers per lane) ----
__global__ void conv_gather_kernel(const int* __restrict__ rowD, const int* __restrict__ srcByDst,
                                   const float* __restrict__ hs, const float* __restrict__ dinv,
                                   const float* __restrict__ b, float* __restrict__ h2, int N) {
    int node = blockIdx.x * 4 + (threadIdx.x >> 6);
    if (node >= N) return;
    int lane = threadIdx.x & 63;
    int half = lane >> 5, d = lane & 31;
    int s = rowD[node], e = rowD[node + 1];
    float a0 = 0.f, a1 = 0.f, a2 = 0.f, a3 = 0.f;
    int k = s + half;
    for (; k + 6 < e; k += 8) {
        int i0 = srcByDst[k];
        int i1 = srcByDst[k + 2];
        int i2 = srcByDst[k + 4];
        int i3 = srcByDst[k + 6];
        a0 += hs[i0 * D + d];
        a1 += hs[i1 * D + d];
        a2 += hs[i2 * D + d];
        a3 += hs[i3 * D + d];
    }
    for (; k < e; k += 2) a0 += hs[srcByDst[k] * D + d];
    float acc = (a0 + a1) + (a2 + a3);
    acc += __shfl_xor(acc, 32);
    if (half == 0) {
        float v = dinv[node] * (acc + hs[node * D + d]) + b[d];
        h2[node * D + d] = fmaxf(v, 0.f);
    }
}

__global__ void pow_gather_kernel(const int* __restrict__ rowS, const int* __restrict__ dstBySrc,
                                  const float* __restrict__ h2, float* __restrict__ out, int N) {
    int node = blockIdx.x * 4 + (threadIdx.x >> 6);
    if (node >= N) return;
    int lane = threadIdx.x & 63;
    int half = lane >> 5, d = lane & 31;
    int s = rowS[node], e = rowS[node + 1];
    float hval = h2[node * D + d];
    float a0 = 0.f, a1 = 0.f, a2 = 0.f, a3 = 0.f;
    int k = s + half;
    for (; k + 6 < e; k += 8) {
        int i0 = dstBySrc[k];
        int i1 = dstBySrc[k + 2];
        int i2 = dstBySrc[k + 4];
        int i3 = dstBySrc[k + 6];
        float v0 = hval - h2[i0 * D + d];
        float v1 = hval - h2[i1 * D + d];
        float v2 = hval - h2[i2 * D + d];
        float v3 = hval - h2[i3 * D + d];
        a0 += v0 * v0; a1 += v1 * v1; a2 += v2 * v2; a3 += v3 * v3;
    }
    for (; k < e; k += 2) {
        float v = hval - h2[dstBySrc[k] * D + d];
        a0 += v * v;
    }
    float acc = (a0 + a1) + (a2 + a3);
    acc += __shfl_xor(acc, 32);
    if (half == 0) {
        float c = fmaxf((float)(e - s), 1.f);
        out[node * D + d] = tanhf(acc / c);
    }
}

// ---------------- fallback (atomic path, round-1) ----------------
__global__ void fb_count(const int* __restrict__ src, const int* __restrict__ dst,
                         int* __restrict__ degI, int* __restrict__ cntI, int E) {
    int j = blockIdx.x * blockDim.x + threadIdx.x;
    if (j < E) {
        atomicAdd(&degI[dst[j]], 1);
        atomicAdd(&cntI[src[j]], 1);
    }
}
__global__ void fb_dinv(const int* __restrict__ degI, float* __restrict__ dinv, int N) {
    int i = blockIdx.x * blockDim.x + threadIdx.x;
    if (i < N) dinv[i] = rsqrtf((float)(degI[i] + 1));
}
__global__ void fb_scatter_conv(const int* __restrict__ src, const int* __restrict__ dst,
                                const float* __restrict__ hs, float* __restrict__ S, int ED) {
    int idx = blockIdx.x * blockDim.x + threadIdx.x;
    if (idx < ED) {
        int j = idx >> 5, d = idx & 31;
        atomicAdd(&S[dst[j] * D + d], hs[src[j] * D + d]);
    }
}
__global__ void fb_h2(float* __restrict__ S, const float* __restrict__ hs,
                      const float* __restrict__ dinv, const float* __restrict__ b, int ND) {
    int idx = blockIdx.x * blockDim.x + threadIdx.x;
    if (idx < ND) {
        int i = idx >> 5, d = idx & 31;
        float v = dinv[i] * (S[idx] + hs[idx]) + b[d];
        S[idx] = fmaxf(v, 0.f);
    }
}
__global__ void fb_edge_pow(const int* __restrict__ src, const int* __restrict__ dst,
                            const float* __restrict__ h2, float* __restrict__ out, int ED) {
    int idx = blockIdx.x * blockDim.x + threadIdx.x;
    if (idx < ED) {
        int j = idx >> 5, d = idx & 31;
        float v = h2[src[j] * D + d] - h2[dst[j] * D + d];
        atomicAdd(&out[src[j] * D + d], v * v);
    }
}
__global__ void fb_finalize(float* __restrict__ out, const int* __restrict__ cntI, int ND) {
    int idx = blockIdx.x * blockDim.x + threadIdx.x;
    if (idx < ND) {
        int i = idx >> 5;
        float c = fmaxf((float)cntI[i], 1.f);
        out[idx] = tanhf(out[idx] / c);
    }
}

extern "C" void kernel_launch(void* const* d_in, const int* in_sizes, int n_in,
                              void* d_out, int out_size, void* d_ws, size_t ws_size,
                              hipStream_t stream) {
    const float* X  = (const float*)d_in[0];
    const int*   ei = (const int*)d_in[1];
    const float* W  = (const float*)d_in[2];
    const float* b  = (const float*)d_in[3];
    int N = in_sizes[0] / D;
    int E = in_sizes[1] / 2;
    const int* src = ei;
    const int* dst = ei + E;
    float* out = (float*)d_out;

    size_t ND = (size_t)N * D;
    int nb = (N + 511) >> CSH;

    unsigned* coarseD = (unsigned*)d_ws;          // E
    unsigned* coarseS = coarseD + E;              // E
    int* srcByDst = (int*)(coarseS + E);          // E
    int* dstBySrc = srcByDst + E;                 // E
    float* hs   = (float*)(dstBySrc + E);         // ND
    float* h2   = hs + ND;                        // ND
    float* dinv = h2 + ND;                        // N
    int* rowD   = (int*)(dinv + N);               // N+1
    int* rowS   = rowD + N + 1;                   // N+1
    int* coffD  = rowS + N + 1;                   // NBMAX+1
    int* coffS  = coffD + NBMAX + 1;              // NBMAX+1
    int* gCurD  = coffS + NBMAX + 1;              // NBMAX
    int* gCurS  = gCurD + NBMAX;                  // NBMAX
    int* bktTotD = gCurS + NBMAX;                 // NBMAX
    int* bktTotS = bktTotD + NBMAX;               // NBMAX
    size_t need = ((size_t)4 * E + 2 * ND + 3 * (size_t)N + 2 + 6 * NBMAX + 2) * 4;

    if (ws_size >= need && nb <= NBMAX && N <= (1 << PSH)) {
        hipMemsetAsync(bktTotD, 0, (size_t)2 * NBMAX * sizeof(int), stream);
        int cgrid = (E + 4095) / 4096;
        ccount_kernel<<<cgrid, 1024, 0, stream>>>(src, dst, bktTotD, bktTotS, E);
        cscan_kernel<<<1, 256, 0, stream>>>(bktTotD, bktTotS, coffD, coffS,
                                            gCurD, gCurS, rowD, rowS, nb, N, E);
        coarse_scatter<<<cgrid, 1024, 0, stream>>>(src, dst, gCurD, gCurS,
                                                   coarseD, coarseS, E);
        fine_build<<<2 * nb, 1024, 0, stream>>>(coarseD, coarseS, coffD, coffS,
                                                rowD, rowS, srcByDst, dstBySrc, dinv, N, nb);
        matmul_scale_kernel<<<(N + 7) / 8, 256, 0, stream>>>(X, W, dinv, hs, N);
        conv_gather_kernel<<<(N + 3) / 4, 256, 0, stream>>>(rowD, srcByDst, hs, dinv, b, h2, N);
        pow_gather_kernel<<<(N + 3) / 4, 256, 0, stream>>>(rowS, dstBySrc, h2, out, N);
    } else {
        float* fhs  = (float*)d_ws;
        float* S    = fhs + ND;
        float* fdv  = S + ND;
        int*   fdeg = (int*)(fdv + N);
        int*   fcnt = fdeg + N;
        hipMemsetAsync(S, 0, ND * sizeof(float), stream);
        hipMemsetAsync(fdeg, 0, (size_t)2 * N * sizeof(int), stream);
        hipMemsetAsync(d_out, 0, ND * sizeof(float), stream);
        int EDi = E * D, NDi = (int)ND;
        fb_count<<<(E + 255) / 256, 256, 0, stream>>>(src, dst, fdeg, fcnt, E);
        fb_dinv<<<(N + 255) / 256, 256, 0, stream>>>(fdeg, fdv, N);
        matmul_scale_kernel<<<(N + 7) / 8, 256, 0, stream>>>(X, W, fdv, fhs, N);
        fb_scatter_conv<<<(EDi + 255) / 256, 256, 0, stream>>>(src, dst, fhs, S, EDi);
        fb_h2<<<(NDi + 255) / 256, 256, 0, stream>>>(S, fhs, fdv, b, NDi);
        fb_edge_pow<<<(EDi + 255) / 256, 256, 0, stream>>>(src, dst, S, out, EDi);
        fb_finalize<<<(NDi + 255) / 256, 256, 0, stream>>>(out, fcnt, NDi);
    }
}